// Round 2
// 345.218 us; speedup vs baseline: 1.3020x; 1.3020x over previous
//
#include <hip/hip_runtime.h>

// Problem constants: B=8, H=256, W=256, C=8, K=16
// S = B*H*W = 524288 source pixels; out pixel q has 136 channels:
//   ch 0..7   = x[q][ch]
//   ch 8+j    = gauss[k][rem] * x[rem][c],  kc = q>>12, k=kc>>3, c=kc&7,
//               rem = (q&4095)*128 + j      (j = 0..127)
// => block r0 (=q&4095) serves ALL 128 out pixels {kc*4096+r0} from ONE
//    128-pixel rem-tile [r0*128, r0*128+128).
#define S_TOTAL 524288u
#define NEG4LOG2PI (-7.3515082656373808f)

typedef float f32x4 __attribute__((ext_vector_type(4)));

// ---------------- prep: invert lower-triangular L_k, compute base_k ----------------
__global__ void prep_kernel(const float* __restrict__ scale,
                            float* __restrict__ minv,
                            float* __restrict__ base) {
    int k = threadIdx.x;
    if (k >= 16) return;
    float L[8][8], M[8][8];
    const float* Ls = scale + k * 64;
    for (int i = 0; i < 8; i++)
        for (int j = 0; j < 8; j++) { L[i][j] = Ls[i * 8 + j]; M[i][j] = 0.f; }
    // column-wise forward substitution: L * M[:,j] = e_j  (lower triangle only)
    for (int j = 0; j < 8; j++) {
        M[j][j] = 1.0f / L[j][j];
        for (int i = j + 1; i < 8; i++) {
            float s = 0.f;
            for (int m = j; m < i; m++) s += L[i][m] * M[m][j];
            M[i][j] = -s / L[i][i];
        }
    }
    float logdet = 0.f;
    for (int i = 0; i < 8; i++) logdet += logf(fabsf(L[i][i]));
    for (int i = 0; i < 8; i++)
        for (int j = 0; j < 8; j++) minv[k * 64 + i * 8 + j] = M[i][j];
    base[k] = -logdet + NEG4LOG2PI;
}

// ---------------- single fused pass ----------------
// grid = 4096 blocks (one per r0), 256 threads.
// Phase 0: stage rem-tile x (transposed by channel), head x, and the 16
//          (M^-1, mu, base) into LDS.
// Phase 1: compute gauss[16][128] for the rem-tile (8 k's per thread).
// Phase 2: write 128 complete 136-float output rows, coalesced float4,
//          nontemporal (streaming, no reuse).
template <bool INLINE_PREP>
__global__ __launch_bounds__(256) void fused_kernel(
    const float* __restrict__ x,
    const float* __restrict__ minv,
    const float* __restrict__ base,
    const float* __restrict__ mean,
    const float* __restrict__ scale,
    float* __restrict__ out)
{
    __shared__ float sM[1024];       // 16 x (8x8) inverse matrices
    __shared__ float sMu[128];       // 16 x 8 means
    __shared__ float sB[16];         // 16 bases
    __shared__ float sXrT[8][128];   // rem-tile x, channel-major
    __shared__ float sGT[16][128];   // gauss, k-major
    __shared__ float sXq[128][8];    // head x for the 128 out pixels

    const unsigned t  = threadIdx.x;
    const unsigned r0 = blockIdx.x;  // 0..4095

    if (INLINE_PREP) {
        if (t < 16u) {
            float L[8][8], M[8][8];
            const float* Ls = scale + t * 64u;
            for (int i = 0; i < 8; i++)
                for (int j = 0; j < 8; j++) { L[i][j] = Ls[i * 8 + j]; M[i][j] = 0.f; }
            for (int j = 0; j < 8; j++) {
                M[j][j] = 1.0f / L[j][j];
                for (int i = j + 1; i < 8; i++) {
                    float s = 0.f;
                    for (int m = j; m < i; m++) s += L[i][m] * M[m][j];
                    M[i][j] = -s / L[i][i];
                }
            }
            float logdet = 0.f;
            for (int i = 0; i < 8; i++) logdet += logf(fabsf(L[i][i]));
            for (int i = 0; i < 8; i++)
                for (int j = 0; j < 8; j++) sM[t * 64u + i * 8 + j] = M[i][j];
            sB[t] = -logdet + NEG4LOG2PI;
        }
    } else {
        for (unsigned i = t; i < 1024u; i += 256u) sM[i] = minv[i];
        if (t < 16u) sB[t] = base[t];
    }
    if (t < 128u) sMu[t] = mean[t];

    // rem-tile x: pixels [r0*128, r0*128+128), coalesced float4, transpose into LDS
    {
        f32x4 v = ((const f32x4*)x)[r0 * 256u + t];   // pixel p = t>>1, half = t&1
        unsigned p = t >> 1, h = (t & 1u) * 4u;
        sXrT[h + 0][p] = v.x; sXrT[h + 1][p] = v.y;
        sXrT[h + 2][p] = v.z; sXrT[h + 3][p] = v.w;
    }
    // head x for out pixels q = kc*4096 + r0 (kc = 0..127): 2 float4 per row
    {
        unsigned kc = t >> 1, h = t & 1u;
        f32x4 v = ((const f32x4*)x)[(kc * 4096u + r0) * 2u + h];
        unsigned b = h * 4u;
        sXq[kc][b + 0] = v.x; sXq[kc][b + 1] = v.y;
        sXq[kc][b + 2] = v.z; sXq[kc][b + 3] = v.w;
    }
    __syncthreads();

    // gauss: thread handles pixel j = t&127, k's [k0, k0+8)
    {
        unsigned j  = t & 127u;
        unsigned k0 = (t >> 7) * 8u;    // wave-uniform
        float xv[8];
        #pragma unroll
        for (int c = 0; c < 8; c++) xv[c] = sXrT[c][j];
        #pragma unroll
        for (unsigned kk = 0; kk < 8u; kk++) {
            unsigned k = k0 + kk;
            const float* M  = &sM[k * 64u];
            const float* mu = &sMu[k * 8u];
            float d[8];
            #pragma unroll
            for (int c = 0; c < 8; c++) d[c] = xv[c] - mu[c];
            float quad = 0.f;
            #pragma unroll
            for (int i = 0; i < 8; i++) {
                float y = 0.f;
                #pragma unroll
                for (int jj = 0; jj <= i; jj++) y = fmaf(M[i * 8 + jj], d[jj], y);
                quad = fmaf(y, y, quad);
            }
            sGT[k][j] = __expf(fmaf(-0.5f, quad, sB[k]));
        }
    }
    __syncthreads();

    // output: 128 rows x 34 float4 = 4352 float4 per block (17 exact passes)
    for (unsigned i = t; i < 4352u; i += 256u) {
        unsigned kc = i / 34u;                 // magic-mul division
        unsigned f4 = i - kc * 34u;
        f32x4 v;
        if (f4 < 2u) {
            v = *(const f32x4*)&sXq[kc][f4 * 4u];
        } else {
            unsigned j0 = f4 * 4u - 8u;        // 0..124, multiple of 4
            unsigned k  = kc >> 3, c = kc & 7u;
            f32x4 g  = *(const f32x4*)&sGT[k][j0];
            f32x4 xc = *(const f32x4*)&sXrT[c][j0];
            v = g * xc;
        }
        float* dst = out + (kc * 4096u + r0) * 136u + f4 * 4u;
        __builtin_nontemporal_store(v, (f32x4*)dst);
    }
}

extern "C" void kernel_launch(void* const* d_in, const int* in_sizes, int n_in,
                              void* d_out, int out_size, void* d_ws, size_t ws_size,
                              hipStream_t stream) {
    const float* x     = (const float*)d_in[0];
    const float* scale = (const float*)d_in[1];
    const float* mean  = (const float*)d_in[2];
    float* out = (float*)d_out;

    const size_t NEED = (1024 + 16) * sizeof(float);
    if (ws_size >= NEED) {
        float* minv = (float*)d_ws;
        float* base = minv + 1024;
        prep_kernel<<<1, 64, 0, stream>>>(scale, minv, base);
        fused_kernel<false><<<4096, 256, 0, stream>>>(x, minv, base, mean, scale, out);
    } else {
        fused_kernel<true><<<4096, 256, 0, stream>>>(x, nullptr, nullptr, mean, scale, out);
    }
}